// Round 9
// baseline (170.588 us; speedup 1.0000x reference)
//
#include <hip/hip_runtime.h>
#include <hip/hip_bf16.h>
#include <cstdint>
#include <cstddef>

using bf16x8   = __attribute__((ext_vector_type(8))) short;
using f32x4    = __attribute__((ext_vector_type(4))) float;
using f32x16   = __attribute__((ext_vector_type(16))) float;
using ushort8  = __attribute__((ext_vector_type(8))) unsigned short;
using ushort4v = __attribute__((ext_vector_type(4))) unsigned short;
using float4v  = __attribute__((ext_vector_type(4))) float;

#define MFMA16(a,b,c) __builtin_amdgcn_mfma_f32_16x16x32_bf16((a),(b),(c),0,0,0)
#define MFMA32(a,b,c) __builtin_amdgcn_mfma_f32_32x32x16_bf16((a),(b),(c),0,0,0)

#define QSCALE 0.18033688011112042f   // log2(e)/8

__device__ __forceinline__ unsigned short f2bf(float f){
    union { float f; unsigned u; } v; v.f = f;
    unsigned r = v.u + 0x7FFFu + ((v.u >> 16) & 1u);
    return (unsigned short)(r >> 16);
}

__device__ __forceinline__ int cvtpk(float lo, float hi){
    int r;
    asm volatile("v_cvt_pk_bf16_f32 %0, %1, %2" : "=v"(r) : "v"(lo), "v"(hi));
    return r;
}

#if __has_builtin(__builtin_amdgcn_permlane32_swap)
__device__ __forceinline__ void plswap(int &a, int &b){
    auto r = __builtin_amdgcn_permlane32_swap(a, b, false, false);
    a = r[0]; b = r[1];
}
#else
__device__ __forceinline__ void plswap(int &a, int &b){
    int ta = __shfl_xor(a, 32), tb = __shfl_xor(b, 32);
    bool hi = ((threadIdx.x & 63) >= 32);
    int na = hi ? tb : a;
    int nb = hi ? b  : ta;
    a = na; b = nb;
}
#endif

__device__ __forceinline__ void gload16(const unsigned short* g, unsigned short* l){
    __builtin_amdgcn_global_load_lds(
        (const __attribute__((address_space(1))) void*)g,
        (__attribute__((address_space(3))) void*)l,
        16, 0, 0);
}

// ---------------------------------------------------------------- gn_stats + wconv merged
__global__ __launch_bounds__(256) void gn_stats_wconv(const float* __restrict__ x,
                                                      float* __restrict__ mean,
                                                      float* __restrict__ rstd,
                                                      const float* __restrict__ w0, const float* __restrict__ w1,
                                                      const float* __restrict__ w2, const float* __restrict__ w3,
                                                      unsigned short* wqk, unsigned short* wv, unsigned short* wo){
    int bid = blockIdx.x;
    if (bid < 64){
        int bg = bid;
        const float4v* p4 = (const float4v*)(x + (size_t)bg * 65536);
        float s = 0.f, ss = 0.f;
        for (int i = threadIdx.x; i < 16384; i += 256){
            float4v v = p4[i];
            s  += v[0]+v[1]+v[2]+v[3];
            ss += v[0]*v[0]+v[1]*v[1]+v[2]*v[2]+v[3]*v[3];
        }
        __shared__ float ls[4], lss[4];
        int lane = threadIdx.x & 63, w = threadIdx.x >> 6;
        #pragma unroll
        for (int o = 32; o > 0; o >>= 1){ s += __shfl_down(s, o); ss += __shfl_down(ss, o); }
        if (lane == 0){ ls[w] = s; lss[w] = ss; }
        __syncthreads();
        if (threadIdx.x == 0){
            float S = ls[0]+ls[1]+ls[2]+ls[3];
            float SS = lss[0]+lss[1]+lss[2]+lss[3];
            float m = S * (1.f/65536.f);
            float var = SS * (1.f/65536.f) - m*m;
            mean[bg] = m;
            rstd[bg] = rsqrtf(var + 1e-5f);
        }
    } else {
        int i2 = bid - 64;
        int y = i2 >> 8, bx = i2 & 255;
        const float* src; unsigned short* dst; float sc = 1.0f;
        switch (y){
            case 0: src = w0; dst = wqk;          sc = QSCALE; break;
            case 1: src = w1; dst = wqk + 512*512; break;
            case 2: src = w2; dst = wv; break;
            default: src = w3; dst = wo; break;
        }
        int i = (bx*256 + threadIdx.x) * 4;
        float4v v = *(const float4v*)(src + i);
        ushort4v o;
        #pragma unroll
        for (int j = 0; j < 4; j++) o[j] = f2bf(v[j]*sc);
        *(ushort4v*)(dst + i) = o;
    }
}

__global__ __launch_bounds__(256) void gn_apply(const float* __restrict__ x,
                                                const float* __restrict__ mean,
                                                const float* __restrict__ rstd,
                                                const float* __restrict__ gw,
                                                const float* __restrict__ gb,
                                                unsigned short* __restrict__ xn){
    int b = blockIdx.z, c0 = blockIdx.y * 64, n0 = blockIdx.x * 64;
    __shared__ unsigned short tile[64][68];
    for (int i = threadIdx.x; i < 64*16; i += 256){
        int row = i >> 4, f4 = i & 15;
        int c = c0 + row;
        int g = b*32 + (c >> 4);
        float rs = rstd[g];
        float wgt = gw[c] * rs;
        float bia = gb[c] - mean[g] * wgt;
        float4v v = *(const float4v*)(x + ((size_t)(b*512 + c))*4096 + n0 + f4*4);
        ushort4v o;
        #pragma unroll
        for (int j = 0; j < 4; j++) o[j] = f2bf(v[j]*wgt + bia);
        *(ushort4v*)&tile[row][f4*4] = o;
    }
    __syncthreads();
    for (int i = threadIdx.x; i < 64*8; i += 256){
        int nr = i >> 3, c8 = i & 7;
        ushort8 o;
        #pragma unroll
        for (int j = 0; j < 8; j++) o[j] = tile[c8*8 + j][nr];
        *(ushort8*)(xn + ((size_t)(b*4096 + n0 + nr))*512 + c0 + c8*8) = o;
    }
}

// ---------------------------------------------------------------- fused QKV projections
__global__ __launch_bounds__(256) void gemm_qkv(const unsigned short* __restrict__ xn,
                                                const unsigned short* __restrict__ wqk,
                                                const unsigned short* __restrict__ Wv,
                                                const float* __restrict__ bq,
                                                const float* __restrict__ bk,
                                                const float* __restrict__ bv,
                                                unsigned short* __restrict__ Q,
                                                unsigned short* __restrict__ K,
                                                unsigned short* __restrict__ Vt){
    __shared__ unsigned short Al[128*32];
    __shared__ unsigned short Bl[128*32];
    int bid = blockIdx.x;
    int t = threadIdx.x, lane = t & 63, w = t >> 6;
    int wr = w >> 1, wc = w & 1;
    int lr = lane >> 2, lc = lane & 3;

    if (bid < 512){
        int m0 = (bid & 63) * 128, n0 = (bid >> 6) * 128;
        f32x4 acc[4][4] = {};
        const unsigned short* Asrc = xn  + (size_t)(m0 + w*32 + lr)*512 + lc*8;
        const unsigned short* Bsrc = wqk + (size_t)(n0 + w*32 + lr)*512 + lc*8;
        unsigned short* Adst = &Al[(w*32)*32];
        unsigned short* Bdst = &Bl[(w*32)*32];

        for (int ks = 0; ks < 16; ks++){
            gload16(Asrc + ks*32,          Adst);
            gload16(Asrc + ks*32 + 16*512, Adst + 16*32);
            gload16(Bsrc + ks*32,          Bdst);
            gload16(Bsrc + ks*32 + 16*512, Bdst + 16*32);
            asm volatile("s_waitcnt vmcnt(0)" ::: "memory");
            __syncthreads();
            bf16x8 a[4], b[4];
            #pragma unroll
            for (int mi = 0; mi < 4; mi++) a[mi] = *(bf16x8*)&Al[(wr*64 + mi*16 + (lane&15))*32 + (lane>>4)*8];
            #pragma unroll
            for (int ni = 0; ni < 4; ni++) b[ni] = *(bf16x8*)&Bl[(wc*64 + ni*16 + (lane&15))*32 + (lane>>4)*8];
            #pragma unroll
            for (int mi = 0; mi < 4; mi++)
                #pragma unroll
                for (int ni = 0; ni < 4; ni++)
                    acc[mi][ni] = MFMA16(a[mi], b[ni], acc[mi][ni]);
            __syncthreads();
        }

        int cK = n0 >> 9;
        const float* bias = cK ? bk : bq;
        unsigned short* dst0 = cK ? K : Q;
        float bsc = cK ? 1.0f : QSCALE;
        #pragma unroll
        for (int mi = 0; mi < 4; mi++)
            #pragma unroll
            for (int ni = 0; ni < 4; ni++)
                #pragma unroll
                for (int r = 0; r < 4; r++){
                    int mrow = m0 + wr*64 + mi*16 + (lane>>4)*4 + r;
                    int col  = (n0 & 511) + wc*64 + ni*16 + (lane&15);
                    int b_ = mrow >> 12, n = mrow & 4095;
                    int h = col >> 6, d = col & 63;
                    float v = acc[mi][ni][r] + bias[col]*bsc;
                    dst0[(size_t)((b_*8+h)*4096 + n)*64 + d] = f2bf(v);
                }
    } else {
        int i2 = bid - 512;
        int m0 = (i2 >> 6) * 64, n0 = (i2 & 63) * 128;   // same-n0 blocks stride 64 -> same XCD
        f32x4 acc[2][4] = {};
        const unsigned short* Asrc = Wv + (size_t)(m0 + w*16 + lr)*512 + lc*8;
        const unsigned short* Bsrc = xn + (size_t)(n0 + w*32 + lr)*512 + lc*8;
        unsigned short* Adst = &Al[(w*16)*32];
        unsigned short* Bdst = &Bl[(w*32)*32];

        for (int ks = 0; ks < 16; ks++){
            gload16(Asrc + ks*32,          Adst);
            gload16(Bsrc + ks*32,          Bdst);
            gload16(Bsrc + ks*32 + 16*512, Bdst + 16*32);
            asm volatile("s_waitcnt vmcnt(0)" ::: "memory");
            __syncthreads();
            bf16x8 a[2], b[4];
            #pragma unroll
            for (int mi = 0; mi < 2; mi++) a[mi] = *(bf16x8*)&Al[(wr*32 + mi*16 + (lane&15))*32 + (lane>>4)*8];
            #pragma unroll
            for (int ni = 0; ni < 4; ni++) b[ni] = *(bf16x8*)&Bl[(wc*64 + ni*16 + (lane&15))*32 + (lane>>4)*8];
            #pragma unroll
            for (int mi = 0; mi < 2; mi++)
                #pragma unroll
                for (int ni = 0; ni < 4; ni++)
                    acc[mi][ni] = MFMA16(a[mi], b[ni], acc[mi][ni]);
            __syncthreads();
        }
        #pragma unroll
        for (int mi = 0; mi < 2; mi++)
            #pragma unroll
            for (int ni = 0; ni < 4; ni++)
                #pragma unroll
                for (int r = 0; r < 4; r++){
                    int row  = m0 + wr*32 + mi*16 + (lane>>4)*4 + r;
                    int colm = n0 + wc*64 + ni*16 + (lane&15);
                    int b_ = colm >> 12, n = colm & 4095;
                    int h = row >> 6, d = row & 63;
                    float v = acc[mi][ni][r] + bv[row];
                    Vt[(size_t)((b_*8+h)*64 + d)*4096 + n] = f2bf(v);
                }
    }
}

// ---------------------------------------------------------------- output projection + residual
// grid (64, 8): x = token tile (n0), y = cout tile (m0) -> same-n0 blocks stride 64 = same XCD.
__global__ __launch_bounds__(256) void gemm_o2(const unsigned short* __restrict__ Wo,
                                               const unsigned short* __restrict__ Om,
                                               const float* __restrict__ bo,
                                               const float* __restrict__ resid,
                                               float* __restrict__ outp){
    __shared__ unsigned short Al[64*32];
    __shared__ unsigned short Bl[128*32];
    int t = threadIdx.x, lane = t & 63, w = t >> 6;
    int wr = w >> 1, wc = w & 1;
    int m0 = blockIdx.y * 64, n0 = blockIdx.x * 128;
    int lr = lane >> 2, lc = lane & 3;
    f32x4 acc[2][4] = {};

    const unsigned short* Asrc = Wo + (size_t)(m0 + w*16 + lr)*512 + lc*8;
    const unsigned short* Bsrc = Om + (size_t)(n0 + w*32 + lr)*512 + lc*8;
    unsigned short* Adst = &Al[(w*16)*32];
    unsigned short* Bdst = &Bl[(w*32)*32];

    for (int ks = 0; ks < 16; ks++){
        gload16(Asrc + ks*32,          Adst);
        gload16(Bsrc + ks*32,          Bdst);
        gload16(Bsrc + ks*32 + 16*512, Bdst + 16*32);
        asm volatile("s_waitcnt vmcnt(0)" ::: "memory");
        __syncthreads();
        bf16x8 a[2], b[4];
        #pragma unroll
        for (int mi = 0; mi < 2; mi++) a[mi] = *(bf16x8*)&Al[(wr*32 + mi*16 + (lane&15))*32 + (lane>>4)*8];
        #pragma unroll
        for (int ni = 0; ni < 4; ni++) b[ni] = *(bf16x8*)&Bl[(wc*64 + ni*16 + (lane&15))*32 + (lane>>4)*8];
        #pragma unroll
        for (int mi = 0; mi < 2; mi++)
            #pragma unroll
            for (int ni = 0; ni < 4; ni++)
                acc[mi][ni] = MFMA16(a[mi], b[ni], acc[mi][ni]);
        __syncthreads();
    }
    #pragma unroll
    for (int mi = 0; mi < 2; mi++)
        #pragma unroll
        for (int ni = 0; ni < 4; ni++)
            #pragma unroll
            for (int r = 0; r < 4; r++){
                int row  = m0 + wr*32 + mi*16 + (lane>>4)*4 + r;
                int colm = n0 + wc*64 + ni*16 + (lane&15);
                int b_ = colm >> 12, n = colm & 4095;
                size_t oi = ((size_t)(b_*512 + row))*4096 + n;
                outp[oi] = acc[mi][ni][r] + bo[row] + resid[oi];
            }
}

// ---------------------------------------------------------------- flash attention v8
// 4096 single-wave blocks: (16 bh) x (64 qt of 64 q) x (4 kv-quarters of 1024).
// KV tile 32; K LDS-dbuf (8KB) + V LDS single (4KB, d-pair rows) = 12KB -> 12 blocks/CU,
// 3 waves/SIMD, ZERO barriers (counted vmcnt only). Writes unnormalized bf16 O-partials + f32 l.
__global__ __launch_bounds__(64, 3) void attn8(const unsigned short* __restrict__ Q,
                                               const unsigned short* __restrict__ K,
                                               const unsigned short* __restrict__ Vt,
                                               unsigned short* __restrict__ Opart,
                                               float* __restrict__ Lpart){
    int bid = blockIdx.x;
    int xcd = bid & 7;
    int idx = bid >> 3;                 // 0..511
    int bh  = (xcd << 1) | (idx >> 8);  // 2 heads per XCD -> K/V in L2
    int rest = idx & 255;
    int qt = rest >> 2;
    int kq = rest & 3;
    int lane = threadIdx.x & 63;
    int ln = lane & 31, hi = lane >> 5;
    int q0 = qt * 64;
    int kvbase = kq * 1024;

    __shared__ unsigned short Kl[2][32*64];   // [kv 32][d 64], swizzled
    __shared__ unsigned short Vl[32*64];      // [d-pair 32][128B], swizzled

    const unsigned short* Qb = Q  + (size_t)bh * 4096 * 64;
    const unsigned short* Kb = K  + (size_t)bh * 4096 * 64;
    const unsigned short* Vb = Vt + (size_t)bh * 64 * 4096;

    bf16x8 bqa[4], bqb[4];
    #pragma unroll
    for (int dsub = 0; dsub < 4; dsub++){
        bqa[dsub] = *(const bf16x8*)(Qb + (size_t)(q0 + ln)*64      + dsub*16 + hi*8);
        bqb[dsub] = *(const bf16x8*)(Qb + (size_t)(q0 + 32 + ln)*64 + dsub*16 + hi*8);
    }

    int srow = lane >> 3;
    int sswz = (lane & 7) ^ srow;                 // logical slot staged into physical lane slot
    int vd   = (srow << 1) + (sswz >> 2);         // V: d for instr 0
    int vkvo = (sswz & 3) * 8;

    auto stageK = [&](int kt){
        int kv0 = kvbase + kt*32;
        unsigned short* dst = &Kl[kt & 1][0];
        #pragma unroll
        for (int i = 0; i < 4; i++)
            gload16(Kb + (size_t)(kv0 + i*8 + srow)*64 + sswz*8, dst + i*512);
    };
    auto stageV = [&](int kt){
        int kv0 = kvbase + kt*32;
        #pragma unroll
        for (int i = 0; i < 4; i++)
            gload16(Vb + (size_t)(vd + i*16)*4096 + kv0 + vkvo, &Vl[i*512]);
    };

    f32x16 o0a, o1a, o0b, o1b, z;
    #pragma unroll
    for (int r = 0; r < 16; r++){ o0a[r]=0.f; o1a[r]=0.f; o0b[r]=0.f; o1b[r]=0.f; z[r]=0.f; }
    float lsA = 0.f, lsB = 0.f;

    const char* Kbase0 = (const char*)&Kl[0][0] + ln*128;
    const char* Vbase0 = (const char*)&Vl[0];
    int kswz  = ln & 7;
    int vrow  = (ln >> 1) * 128;
    int vswzr = (ln >> 1) & 7;
    int vlnb  = (ln & 1) << 2;

    // prologue: outstanding = [K0, V0, K1]
    stageK(0);
    stageV(0);
    stageK(1);

    for (int kt = 0; kt < 32; kt++){
        if (kt < 31) asm volatile("s_waitcnt vmcnt(4)" ::: "memory");
        else         asm volatile("s_waitcnt vmcnt(0)" ::: "memory");
        __builtin_amdgcn_sched_barrier(0);
        int boff = (kt & 1) * (32*64*2);

        // ---- QK^T (swapped): S^T[kv 32][q], two q-sets share each K frag
        f32x16 sA, sB;
        {
            bf16x8 ak = *(const bf16x8*)(Kbase0 + boff + ((hi ^ kswz) << 4));
            sA = MFMA32(ak, bqa[0], z);
            sB = MFMA32(ak, bqb[0], z);
        }
        __builtin_amdgcn_s_setprio(1);
        #pragma unroll
        for (int dsub = 1; dsub < 4; dsub++){
            bf16x8 ak = *(const bf16x8*)(Kbase0 + boff + ((((dsub<<1)|hi) ^ kswz) << 4));
            sA = MFMA32(ak, bqa[dsub], sA);
            sB = MFMA32(ak, bqb[dsub], sB);
        }
        __builtin_amdgcn_s_setprio(0);

        // ---- p = exp2(s); row-sums
        #pragma unroll
        for (int r = 0; r < 16; r++){ sA[r] = __builtin_amdgcn_exp2f(sA[r]); lsA += sA[r]; }
        #pragma unroll
        for (int r = 0; r < 16; r++){ sB[r] = __builtin_amdgcn_exp2f(sB[r]); lsB += sB[r]; }

        // ---- PV (swapped): each V frag feeds both q-sets
        __builtin_amdgcn_s_setprio(1);
        #pragma unroll
        for (int ksub = 0; ksub < 2; ksub++){
            int obp = ksub * 8;
            int a0 = cvtpk(sA[obp+0], sA[obp+1]);
            int a1 = cvtpk(sA[obp+2], sA[obp+3]);
            int c0 = cvtpk(sA[obp+4], sA[obp+5]);
            int c1 = cvtpk(sA[obp+6], sA[obp+7]);
            plswap(a0, c0); plswap(a1, c1);
            union { int i[4]; bf16x8 v; } fuA;
            fuA.i[0] = a0; fuA.i[1] = a1; fuA.i[2] = c0; fuA.i[3] = c1;

            int d0 = cvtpk(sB[obp+0], sB[obp+1]);
            int d1 = cvtpk(sB[obp+2], sB[obp+3]);
            int e0 = cvtpk(sB[obp+4], sB[obp+5]);
            int e1 = cvtpk(sB[obp+6], sB[obp+7]);
            plswap(d0, e0); plswap(d1, e1);
            union { int i[4]; bf16x8 v; } fuB;
            fuB.i[0] = d0; fuB.i[1] = d1; fuB.i[2] = e0; fuB.i[3] = e1;

            int vs = (((vlnb | (ksub<<1) | hi) ^ vswzr) << 4);
            bf16x8 av0 = *(const bf16x8*)(Vbase0 + vrow + vs);
            bf16x8 av1 = *(const bf16x8*)(Vbase0 + 16*128 + vrow + vs);
            o0a = MFMA32(av0, fuA.v, o0a);
            o1a = MFMA32(av1, fuA.v, o1a);
            o0b = MFMA32(av0, fuB.v, o0b);
            o1b = MFMA32(av1, fuB.v, o1b);
        }
        __builtin_amdgcn_s_setprio(0);

        // stage next: V(t+1) (after PV reads complete - program order), K(t+2)
        __builtin_amdgcn_sched_barrier(0);
        if (kt < 31) stageV(kt + 1);
        if (kt < 30) stageK(kt + 2);
        __builtin_amdgcn_sched_barrier(0);
    }

    // ---- epilogue: unnormalized partials
    lsA += __shfl_xor(lsA, 32);
    lsB += __shfl_xor(lsB, 32);
    size_t obase = ((size_t)(kq*16 + bh))*4096 + q0;
    if (hi == 0){
        Lpart[obase + ln]      = lsA;
        Lpart[obase + 32 + ln] = lsB;
    }
    unsigned short* dA = Opart + (obase + ln)*64;
    unsigned short* dB = Opart + (obase + 32 + ln)*64;
    #pragma unroll
    for (int m = 0; m < 2; m++){
        const f32x16& ovA = m ? o1a : o0a;
        const f32x16& ovB = m ? o1b : o0b;
        #pragma unroll
        for (int g = 0; g < 4; g++){
            int d = m*32 + g*8 + hi*4;
            ushort4v pkA, pkB;
            #pragma unroll
            for (int j = 0; j < 4; j++){
                pkA[j] = f2bf(ovA[g*4 + j]);
                pkB[j] = f2bf(ovB[g*4 + j]);
            }
            *(ushort4v*)(dA + d) = pkA;
            *(ushort4v*)(dB + d) = pkB;
        }
    }
}

// merge 4 kv-quarter partials -> Om (bf16). grid 2048 x 256, 8 outputs/thread.
__global__ __launch_bounds__(256) void attn_merge(const unsigned short* __restrict__ Op,
                                                  const float* __restrict__ Lp,
                                                  unsigned short* __restrict__ Om){
    int g = blockIdx.x*256 + threadIdx.x;
    int token = g >> 6;
    int cc = g & 63;
    int h = cc >> 3, dd = (cc & 7)*8;
    int b = token >> 12, n = token & 4095;
    int bh = b*8 + h;
    float acc[8] = {};
    float l = 0.f;
    #pragma unroll
    for (int kq = 0; kq < 4; kq++){
        size_t row = ((size_t)(kq*16 + bh))*4096 + n;
        ushort8 ov = *(const ushort8*)(Op + row*64 + dd);
        #pragma unroll
        for (int j = 0; j < 8; j++){
            union { unsigned u; float f; } cv;
            cv.u = ((unsigned)(unsigned short)ov[j]) << 16;
            acc[j] += cv.f;
        }
        l += Lp[row];
    }
    float r = 1.0f / l;
    ushort8 o;
    #pragma unroll
    for (int j = 0; j < 8; j++) o[j] = f2bf(acc[j]*r);
    *(ushort8*)(Om + (size_t)token*512 + h*64 + dd) = o;
}

// ---------------------------------------------------------------- flash attention v5 (fallback if ws too small)
__global__ __launch_bounds__(128, 2) void attn5(const unsigned short* __restrict__ Q,
                                                const unsigned short* __restrict__ K,
                                                const unsigned short* __restrict__ Vt,
                                                unsigned short* __restrict__ O){
    int bid = blockIdx.x;
    int idx = bid >> 3;
    int bh = ((bid & 7) << 1) | (idx >> 6);
    int qt = idx & 63;
    int t = threadIdx.x, lane = t & 63, w = t >> 6;
    int ln = lane & 31, hi = lane >> 5;
    int q0 = qt * 64;

    __shared__ unsigned short Kl[2][64*64];
    __shared__ unsigned short Vl[2][64*64];

    const unsigned short* Qb = Q  + (size_t)bh * 4096 * 64;
    const unsigned short* Kb = K  + (size_t)bh * 4096 * 64;
    const unsigned short* Vb = Vt + (size_t)bh * 64 * 4096;

    bf16x8 bqa[4], bqb[4];
    #pragma unroll
    for (int dsub = 0; dsub < 4; dsub++){
        bqa[dsub] = *(const bf16x8*)(Qb + (size_t)(q0 + ln)*64      + dsub*16 + hi*8);
        bqb[dsub] = *(const bf16x8*)(Qb + (size_t)(q0 + 32 + ln)*64 + dsub*16 + hi*8);
    }

    int srow = lane >> 3;
    int sswz = (lane & 7) ^ srow;

    auto stage = [&](int buf, int kt){
        int kv0 = kt * 64;
        #pragma unroll
        for (int i = 0; i < 4; i++){
            int r0 = w*32 + i*8;
            gload16(Kb + (size_t)(kv0 + r0 + srow)*64 + sswz*8, &Kl[buf][r0*64]);
        }
        #pragma unroll
        for (int i = 0; i < 4; i++){
            int r0 = w*32 + i*8;
            gload16(Vb + (size_t)(r0 + srow)*4096 + kv0 + sswz*8, &Vl[buf][r0*64]);
        }
    };

    stage(0, 0);

    f32x16 o0a, o1a, o0b, o1b, z;
    #pragma unroll
    for (int r = 0; r < 16; r++){ o0a[r]=0.f; o1a[r]=0.f; o0b[r]=0.f; o1b[r]=0.f; z[r]=0.f; }
    float lsA = 0.f, lsB = 0.f;

    const char* KbA = (const char*)&Kl[0][0] + (w*32 + ln)*128;
    const char* VbA = (const char*)&Vl[0][0] + ln*128;
    int swzr = (ln & 7) << 4;

    for (int kt = 0; kt < 64; kt++){
        asm volatile("s_waitcnt vmcnt(0)" ::: "memory");
        __builtin_amdgcn_s_barrier();
        __builtin_amdgcn_sched_barrier(0);
        if (kt < 63) stage((kt + 1) & 1, kt + 1);
        __builtin_amdgcn_sched_barrier(0);

        int boff = (kt & 1) * (64*64*2);

        f32x16 sA, sB;
        {
            int cb = (hi*16) ^ swzr;
            bf16x8 ak = *(const bf16x8*)(KbA + boff + cb);
            sA = MFMA32(ak, bqa[0], z);
            sB = MFMA32(ak, bqb[0], z);
        }
        __builtin_amdgcn_s_setprio(1);
        #pragma unroll
        for (int dsub = 1; dsub < 4; dsub++){
            int cb = (dsub*32 + hi*16) ^ swzr;
            bf16x8 ak = *(const bf16x8*)(KbA + boff + cb);
            sA = MFMA32(ak, bqa[dsub], sA);
            sB = MFMA32(ak, bqb[dsub], sB);
        }
        __builtin_amdgcn_s_setprio(0);

        #pragma unroll
        for (int r = 0; r < 16; r++){ sA[r] = __builtin_amdgcn_exp2f(sA[r]); lsA += sA[r]; }
        #pragma unroll
        for (int r = 0; r < 16; r++){ sB[r] = __builtin_amdgcn_exp2f(sB[r]); lsB += sB[r]; }

        __builtin_amdgcn_s_setprio(1);
        #pragma unroll
        for (int hsel = 0; hsel < 2; hsel++){
            int obp = hsel * 8;
            int a0 = cvtpk(sA[obp+0], sA[obp+1]);
            int a1 = cvtpk(sA[obp+2], sA[obp+3]);
            int c0 = cvtpk(sA[obp+4], sA[obp+5]);
            int c1 = cvtpk(sA[obp+6], sA[obp+7]);
            plswap(a0, c0);
            plswap(a1, c1);
            union { int i[4]; bf16x8 v; } fuA;
            fuA.i[0] = a0; fuA.i[1] = a1; fuA.i[2] = c0; fuA.i[3] = c1;

            int d0 = cvtpk(sB[obp+0], sB[obp+1]);
            int d1 = cvtpk(sB[obp+2], sB[obp+3]);
            int e0 = cvtpk(sB[obp+4], sB[obp+5]);
            int e1 = cvtpk(sB[obp+6], sB[obp+7]);
            plswap(d0, e0);
            plswap(d1, e1);
            union { int i[4]; bf16x8 v; } fuB;
            fuB.i[0] = d0; fuB.i[1] = d1; fuB.i[2] = e0; fuB.i[3] = e1;

            int cb = ((w*4 + hsel*2 + hi) << 4) ^ swzr;
            bf16x8 av0 = *(const bf16x8*)(VbA + boff + cb);
            bf16x8 av1 = *(const bf16x8*)(VbA + boff + 32*128 + cb);
            o0a = MFMA32(av0, fuA.v, o0a);
            o1a = MFMA32(av1, fuA.v, o1a);
            o0b = MFMA32(av0, fuB.v, o0b);
            o1b = MFMA32(av1, fuB.v, o1b);
        }
        __builtin_amdgcn_s_setprio(0);
    }

    lsA += __shfl_xor(lsA, 32);
    lsB += __shfl_xor(lsB, 32);
    __syncthreads();
    float* m1 = (float*)&Kl[0][0];
    float* m2 = (float*)&Vl[0][0];
    if (w == 1){
        #pragma unroll
        for (int r = 0; r < 16; r++){
            m1[r*64 + lane]        = o0a[r];
            m1[1024 + r*64 + lane] = o1a[r];
            m2[r*64 + lane]        = o0b[r];
            m2[1024 + r*64 + lane] = o1b[r];
        }
        if (hi == 0){ m2[2048 + ln] = lsA; m2[2048 + 32 + ln] = lsB; }
    }
    __syncthreads();
    if (w == 0){
        #pragma unroll
        for (int r = 0; r < 16; r++){
            o0a[r] += m1[r*64 + lane];
            o1a[r] += m1[1024 + r*64 + lane];
            o0b[r] += m2[r*64 + lane];
            o1b[r] += m2[1024 + r*64 + lane];
        }
        float rA = 1.0f / (lsA + m2[2048 + ln]);
        float rB = 1.0f / (lsB + m2[2048 + 32 + ln]);
        int b = bh >> 3, h = bh & 7;
        unsigned short* dstA = O + (size_t)(b*4096 + q0 + ln)*512      + h*64;
        unsigned short* dstB = O + (size_t)(b*4096 + q0 + 32 + ln)*512 + h*64;
        #pragma unroll
        for (int m = 0; m < 2; m++){
            const f32x16& ovA = m ? o1a : o0a;
            const f32x16& ovB = m ? o1b : o0b;
            #pragma unroll
            for (int g = 0; g < 4; g++){
                int d = m*32 + g*8 + hi*4;
                ushort4v pkA, pkB;
                #pragma unroll
                for (int j = 0; j < 4; j++){
                    pkA[j] = f2bf(ovA[g*4 + j] * rA);
                    pkB[j] = f2bf(ovB[g*4 + j] * rB);
                }
                *(ushort4v*)(dstA + d) = pkA;
                *(ushort4v*)(dstB + d) = pkB;
            }
        }
    }
}

// ---------------------------------------------------------------- launch
extern "C" void kernel_launch(void* const* d_in, const int* in_sizes, int n_in,
                              void* d_out, int out_size, void* d_ws, size_t ws_size,
                              hipStream_t stream) {
    const float* q    = (const float*)d_in[0];
    const float* gn_w = (const float*)d_in[1];
    const float* gn_b = (const float*)d_in[2];
    const float* wq   = (const float*)d_in[3];
    const float* bq   = (const float*)d_in[4];
    const float* wk   = (const float*)d_in[5];
    const float* bk   = (const float*)d_in[6];
    const float* wv   = (const float*)d_in[7];
    const float* bv   = (const float*)d_in[8];
    const float* wo   = (const float*)d_in[9];
    const float* bo   = (const float*)d_in[10];
    float* outp = (float*)d_out;

    char* ws = (char*)d_ws;
    float* mean = (float*)ws;
    float* rstd = (float*)(ws + 256);
    unsigned short* xn  = (unsigned short*)(ws + 1024);
    const size_t TOK = (size_t)8192 * 512;
    unsigned short* wqkb = xn + TOK;
    unsigned short* wvb  = wqkb + 1024*512;
    unsigned short* wob  = wvb + 512*512;
    unsigned short* Qb   = wob + 512*512;
    unsigned short* Kb   = Qb + TOK;
    unsigned short* Vt   = Kb + TOK;
    unsigned short* Ob   = Vt + TOK;
    unsigned short* Opart = Ob + TOK;            // 16.8M shorts = 33.6 MB
    float* Lpart = (float*)(Opart + 4*TOK);      // 262144 floats

    size_t need = (size_t)(Opart - xn + 4*TOK)*2 + 1024 + 262144*4;
    bool big = ws_size >= need;

    gn_stats_wconv<<<1088, 256, 0, stream>>>(q, mean, rstd, wq, wk, wv, wo, wqkb, wvb, wob);
    gn_apply<<<dim3(64, 8, 2), 256, 0, stream>>>(q, mean, rstd, gn_w, gn_b, xn);
    gemm_qkv<<<1024, 256, 0, stream>>>(xn, wqkb, wvb, bq, bk, bv, Qb, Kb, Vt);
    if (big){
        attn8<<<4096, 64, 0, stream>>>(Qb, Kb, Vt, Opart, Lpart);
        attn_merge<<<2048, 256, 0, stream>>>(Opart, Lpart, Ob);
    } else {
        attn5<<<1024, 128, 0, stream>>>(Qb, Kb, Vt, Ob);
    }
    gemm_o2<<<dim3(64, 8), 256, 0, stream>>>(wob, Ob, bo, q, outp);
}

// Round 10
// 135.144 us; speedup vs baseline: 1.2623x; 1.2623x over previous
//
#include <hip/hip_runtime.h>
#include <hip/hip_bf16.h>
#include <cstdint>
#include <cstddef>

using bf16x8   = __attribute__((ext_vector_type(8))) short;
using f32x4    = __attribute__((ext_vector_type(4))) float;
using f32x16   = __attribute__((ext_vector_type(16))) float;
using ushort8  = __attribute__((ext_vector_type(8))) unsigned short;
using ushort4v = __attribute__((ext_vector_type(4))) unsigned short;
using float4v  = __attribute__((ext_vector_type(4))) float;
using float2v  = __attribute__((ext_vector_type(2))) float;

#define MFMA16(a,b,c) __builtin_amdgcn_mfma_f32_16x16x32_bf16((a),(b),(c),0,0,0)
#define MFMA32(a,b,c) __builtin_amdgcn_mfma_f32_32x32x16_bf16((a),(b),(c),0,0,0)

#define QSCALE 0.18033688011112042f   // log2(e)/8

__device__ __forceinline__ unsigned short f2bf(float f){
    union { float f; unsigned u; } v; v.f = f;
    unsigned r = v.u + 0x7FFFu + ((v.u >> 16) & 1u);
    return (unsigned short)(r >> 16);
}

__device__ __forceinline__ int cvtpk(float lo, float hi){
    int r;
    asm volatile("v_cvt_pk_bf16_f32 %0, %1, %2" : "=v"(r) : "v"(lo), "v"(hi));
    return r;
}

#if __has_builtin(__builtin_amdgcn_permlane32_swap)
__device__ __forceinline__ void plswap(int &a, int &b){
    auto r = __builtin_amdgcn_permlane32_swap(a, b, false, false);
    a = r[0]; b = r[1];
}
#else
__device__ __forceinline__ void plswap(int &a, int &b){
    int ta = __shfl_xor(a, 32), tb = __shfl_xor(b, 32);
    bool hi = ((threadIdx.x & 63) >= 32);
    int na = hi ? tb : a;
    int nb = hi ? b  : ta;
    a = na; b = nb;
}
#endif

__device__ __forceinline__ void gload16(const unsigned short* g, unsigned short* l){
    __builtin_amdgcn_global_load_lds(
        (const __attribute__((address_space(1))) void*)g,
        (__attribute__((address_space(3))) void*)l,
        16, 0, 0);
}

// ---------------------------------------------------------------- GN partial stats + wconv merged
// blocks 0-511: partial (sum, sumsq) for group g = bid>>3, eighth e = bid&7 (8192 floats each).
// blocks 512-1535: weight fp32->bf16.
__global__ __launch_bounds__(256) void gn_stats_wconv(const float* __restrict__ x,
                                                      float2v* __restrict__ parts,
                                                      const float* __restrict__ w0, const float* __restrict__ w1,
                                                      const float* __restrict__ w2, const float* __restrict__ w3,
                                                      unsigned short* wqk, unsigned short* wv, unsigned short* wo){
    int bid = blockIdx.x;
    if (bid < 512){
        const float4v* p4 = (const float4v*)(x + (size_t)bid * 8192);
        float s = 0.f, ss = 0.f;
        #pragma unroll
        for (int i = 0; i < 8; i++){
            float4v v = p4[i*256 + threadIdx.x];
            s  += v[0]+v[1]+v[2]+v[3];
            ss += v[0]*v[0]+v[1]*v[1]+v[2]*v[2]+v[3]*v[3];
        }
        __shared__ float ls[4], lss[4];
        int lane = threadIdx.x & 63, w = threadIdx.x >> 6;
        #pragma unroll
        for (int o = 32; o > 0; o >>= 1){ s += __shfl_down(s, o); ss += __shfl_down(ss, o); }
        if (lane == 0){ ls[w] = s; lss[w] = ss; }
        __syncthreads();
        if (threadIdx.x == 0){
            float2v p;
            p[0] = ls[0]+ls[1]+ls[2]+ls[3];
            p[1] = lss[0]+lss[1]+lss[2]+lss[3];
            parts[bid] = p;
        }
    } else {
        int i2 = bid - 512;
        int y = i2 >> 8, bx = i2 & 255;
        const float* src; unsigned short* dst; float sc = 1.0f;
        switch (y){
            case 0: src = w0; dst = wqk;          sc = QSCALE; break;
            case 1: src = w1; dst = wqk + 512*512; break;
            case 2: src = w2; dst = wv; break;
            default: src = w3; dst = wo; break;
        }
        int i = (bx*256 + threadIdx.x) * 4;
        float4v v = *(const float4v*)(src + i);
        ushort4v o;
        #pragma unroll
        for (int j = 0; j < 4; j++) o[j] = f2bf(v[j]*sc);
        *(ushort4v*)(dst + i) = o;
    }
}

// normalize + transpose; folds the 8 partials per group inline (deterministic).
__global__ __launch_bounds__(256) void gn_apply(const float* __restrict__ x,
                                                const float2v* __restrict__ parts,
                                                const float* __restrict__ gw,
                                                const float* __restrict__ gb,
                                                unsigned short* __restrict__ xn){
    int b = blockIdx.z, c0 = blockIdx.y * 64, n0 = blockIdx.x * 64;
    __shared__ unsigned short tile[64][68];
    __shared__ float gmean[4], grstd[4];
    // 4 groups cover channels [c0, c0+64): group index g = b*32 + c0/16 + gl
    if (threadIdx.x < 4){
        int g = b*32 + (c0 >> 4) + threadIdx.x;
        float s = 0.f, ss = 0.f;
        #pragma unroll
        for (int e = 0; e < 8; e++){
            float2v p = parts[g*8 + e];
            s += p[0]; ss += p[1];
        }
        float m = s * (1.f/65536.f);
        float var = ss * (1.f/65536.f) - m*m;
        gmean[threadIdx.x] = m;
        grstd[threadIdx.x] = rsqrtf(var + 1e-5f);
    }
    __syncthreads();
    for (int i = threadIdx.x; i < 64*16; i += 256){
        int row = i >> 4, f4 = i & 15;
        int c = c0 + row;
        int gl = row >> 4;
        float rs = grstd[gl];
        float wgt = gw[c] * rs;
        float bia = gb[c] - gmean[gl] * wgt;
        float4v v = *(const float4v*)(x + ((size_t)(b*512 + c))*4096 + n0 + f4*4);
        ushort4v o;
        #pragma unroll
        for (int j = 0; j < 4; j++) o[j] = f2bf(v[j]*wgt + bia);
        *(ushort4v*)&tile[row][f4*4] = o;
    }
    __syncthreads();
    for (int i = threadIdx.x; i < 64*8; i += 256){
        int nr = i >> 3, c8 = i & 7;
        ushort8 o;
        #pragma unroll
        for (int j = 0; j < 8; j++) o[j] = tile[c8*8 + j][nr];
        *(ushort8*)(xn + ((size_t)(b*4096 + n0 + nr))*512 + c0 + c8*8) = o;
    }
}

// ---------------------------------------------------------------- fused QKV projections
__global__ __launch_bounds__(256) void gemm_qkv(const unsigned short* __restrict__ xn,
                                                const unsigned short* __restrict__ wqk,
                                                const unsigned short* __restrict__ Wv,
                                                const float* __restrict__ bq,
                                                const float* __restrict__ bk,
                                                const float* __restrict__ bv,
                                                unsigned short* __restrict__ Q,
                                                unsigned short* __restrict__ K,
                                                unsigned short* __restrict__ Vt){
    __shared__ unsigned short Al[128*32];
    __shared__ unsigned short Bl[128*32];
    int bid = blockIdx.x;
    int t = threadIdx.x, lane = t & 63, w = t >> 6;
    int wr = w >> 1, wc = w & 1;
    int lr = lane >> 2, lc = lane & 3;

    if (bid < 512){
        int m0 = (bid & 63) * 128, n0 = (bid >> 6) * 128;
        f32x4 acc[4][4] = {};
        const unsigned short* Asrc = xn  + (size_t)(m0 + w*32 + lr)*512 + lc*8;
        const unsigned short* Bsrc = wqk + (size_t)(n0 + w*32 + lr)*512 + lc*8;
        unsigned short* Adst = &Al[(w*32)*32];
        unsigned short* Bdst = &Bl[(w*32)*32];

        for (int ks = 0; ks < 16; ks++){
            gload16(Asrc + ks*32,          Adst);
            gload16(Asrc + ks*32 + 16*512, Adst + 16*32);
            gload16(Bsrc + ks*32,          Bdst);
            gload16(Bsrc + ks*32 + 16*512, Bdst + 16*32);
            asm volatile("s_waitcnt vmcnt(0)" ::: "memory");
            __syncthreads();
            bf16x8 a[4], b[4];
            #pragma unroll
            for (int mi = 0; mi < 4; mi++) a[mi] = *(bf16x8*)&Al[(wr*64 + mi*16 + (lane&15))*32 + (lane>>4)*8];
            #pragma unroll
            for (int ni = 0; ni < 4; ni++) b[ni] = *(bf16x8*)&Bl[(wc*64 + ni*16 + (lane&15))*32 + (lane>>4)*8];
            #pragma unroll
            for (int mi = 0; mi < 4; mi++)
                #pragma unroll
                for (int ni = 0; ni < 4; ni++)
                    acc[mi][ni] = MFMA16(a[mi], b[ni], acc[mi][ni]);
            __syncthreads();
        }

        int cK = n0 >> 9;
        const float* bias = cK ? bk : bq;
        unsigned short* dst0 = cK ? K : Q;
        float bsc = cK ? 1.0f : QSCALE;
        #pragma unroll
        for (int mi = 0; mi < 4; mi++)
            #pragma unroll
            for (int ni = 0; ni < 4; ni++)
                #pragma unroll
                for (int r = 0; r < 4; r++){
                    int mrow = m0 + wr*64 + mi*16 + (lane>>4)*4 + r;
                    int col  = (n0 & 511) + wc*64 + ni*16 + (lane&15);
                    int b_ = mrow >> 12, n = mrow & 4095;
                    int h = col >> 6, d = col & 63;
                    float v = acc[mi][ni][r] + bias[col]*bsc;
                    dst0[(size_t)((b_*8+h)*4096 + n)*64 + d] = f2bf(v);
                }
    } else {
        int i2 = bid - 512;
        int m0 = (i2 >> 6) * 64, n0 = (i2 & 63) * 128;
        f32x4 acc[2][4] = {};
        const unsigned short* Asrc = Wv + (size_t)(m0 + w*16 + lr)*512 + lc*8;
        const unsigned short* Bsrc = xn + (size_t)(n0 + w*32 + lr)*512 + lc*8;
        unsigned short* Adst = &Al[(w*16)*32];
        unsigned short* Bdst = &Bl[(w*32)*32];

        for (int ks = 0; ks < 16; ks++){
            gload16(Asrc + ks*32,          Adst);
            gload16(Bsrc + ks*32,          Bdst);
            gload16(Bsrc + ks*32 + 16*512, Bdst + 16*32);
            asm volatile("s_waitcnt vmcnt(0)" ::: "memory");
            __syncthreads();
            bf16x8 a[2], b[4];
            #pragma unroll
            for (int mi = 0; mi < 2; mi++) a[mi] = *(bf16x8*)&Al[(wr*32 + mi*16 + (lane&15))*32 + (lane>>4)*8];
            #pragma unroll
            for (int ni = 0; ni < 4; ni++) b[ni] = *(bf16x8*)&Bl[(wc*64 + ni*16 + (lane&15))*32 + (lane>>4)*8];
            #pragma unroll
            for (int mi = 0; mi < 2; mi++)
                #pragma unroll
                for (int ni = 0; ni < 4; ni++)
                    acc[mi][ni] = MFMA16(a[mi], b[ni], acc[mi][ni]);
            __syncthreads();
        }
        #pragma unroll
        for (int mi = 0; mi < 2; mi++)
            #pragma unroll
            for (int ni = 0; ni < 4; ni++)
                #pragma unroll
                for (int r = 0; r < 4; r++){
                    int row  = m0 + wr*32 + mi*16 + (lane>>4)*4 + r;
                    int colm = n0 + wc*64 + ni*16 + (lane&15);
                    int b_ = colm >> 12, n = colm & 4095;
                    int h = row >> 6, d = row & 63;
                    float v = acc[mi][ni][r] + bv[row];
                    Vt[(size_t)((b_*8+h)*64 + d)*4096 + n] = f2bf(v);
                }
    }
}

// ---------------------------------------------------------------- output projection + residual
__global__ __launch_bounds__(256) void gemm_o2(const unsigned short* __restrict__ Wo,
                                               const unsigned short* __restrict__ Om,
                                               const float* __restrict__ bo,
                                               const float* __restrict__ resid,
                                               float* __restrict__ outp){
    __shared__ unsigned short Al[64*32];
    __shared__ unsigned short Bl[128*32];
    int t = threadIdx.x, lane = t & 63, w = t >> 6;
    int wr = w >> 1, wc = w & 1;
    int m0 = blockIdx.y * 64, n0 = blockIdx.x * 128;
    int lr = lane >> 2, lc = lane & 3;
    f32x4 acc[2][4] = {};

    const unsigned short* Asrc = Wo + (size_t)(m0 + w*16 + lr)*512 + lc*8;
    const unsigned short* Bsrc = Om + (size_t)(n0 + w*32 + lr)*512 + lc*8;
    unsigned short* Adst = &Al[(w*16)*32];
    unsigned short* Bdst = &Bl[(w*32)*32];

    for (int ks = 0; ks < 16; ks++){
        gload16(Asrc + ks*32,          Adst);
        gload16(Bsrc + ks*32,          Bdst);
        gload16(Bsrc + ks*32 + 16*512, Bdst + 16*32);
        asm volatile("s_waitcnt vmcnt(0)" ::: "memory");
        __syncthreads();
        bf16x8 a[2], b[4];
        #pragma unroll
        for (int mi = 0; mi < 2; mi++) a[mi] = *(bf16x8*)&Al[(wr*32 + mi*16 + (lane&15))*32 + (lane>>4)*8];
        #pragma unroll
        for (int ni = 0; ni < 4; ni++) b[ni] = *(bf16x8*)&Bl[(wc*64 + ni*16 + (lane&15))*32 + (lane>>4)*8];
        #pragma unroll
        for (int mi = 0; mi < 2; mi++)
            #pragma unroll
            for (int ni = 0; ni < 4; ni++)
                acc[mi][ni] = MFMA16(a[mi], b[ni], acc[mi][ni]);
        __syncthreads();
    }
    #pragma unroll
    for (int mi = 0; mi < 2; mi++)
        #pragma unroll
        for (int ni = 0; ni < 4; ni++)
            #pragma unroll
            for (int r = 0; r < 4; r++){
                int row  = m0 + wr*32 + mi*16 + (lane>>4)*4 + r;
                int colm = n0 + wc*64 + ni*16 + (lane&15);
                int b_ = colm >> 12, n = colm & 4095;
                size_t oi = ((size_t)(b_*512 + row))*4096 + n;
                outp[oi] = acc[mi][ni][r] + bo[row] + resid[oi];
            }
}

// ---------------------------------------------------------------- flash attention v5 (proven 95us plateau)
__global__ __launch_bounds__(128, 2) void attn5(const unsigned short* __restrict__ Q,
                                                const unsigned short* __restrict__ K,
                                                const unsigned short* __restrict__ Vt,
                                                unsigned short* __restrict__ O){
    int bid = blockIdx.x;
    int idx = bid >> 3;
    int bh = ((bid & 7) << 1) | (idx >> 6);
    int qt = idx & 63;
    int t = threadIdx.x, lane = t & 63, w = t >> 6;
    int ln = lane & 31, hi = lane >> 5;
    int q0 = qt * 64;

    __shared__ unsigned short Kl[2][64*64];
    __shared__ unsigned short Vl[2][64*64];

    const unsigned short* Qb = Q  + (size_t)bh * 4096 * 64;
    const unsigned short* Kb = K  + (size_t)bh * 4096 * 64;
    const unsigned short* Vb = Vt + (size_t)bh * 64 * 4096;

    bf16x8 bqa[4], bqb[4];
    #pragma unroll
    for (int dsub = 0; dsub < 4; dsub++){
        bqa[dsub] = *(const bf16x8*)(Qb + (size_t)(q0 + ln)*64      + dsub*16 + hi*8);
        bqb[dsub] = *(const bf16x8*)(Qb + (size_t)(q0 + 32 + ln)*64 + dsub*16 + hi*8);
    }

    int srow = lane >> 3;
    int sswz = (lane & 7) ^ srow;

    auto stage = [&](int buf, int kt){
        int kv0 = kt * 64;
        #pragma unroll
        for (int i = 0; i < 4; i++){
            int r0 = w*32 + i*8;
            gload16(Kb + (size_t)(kv0 + r0 + srow)*64 + sswz*8, &Kl[buf][r0*64]);
        }
        #pragma unroll
        for (int i = 0; i < 4; i++){
            int r0 = w*32 + i*8;
            gload16(Vb + (size_t)(r0 + srow)*4096 + kv0 + sswz*8, &Vl[buf][r0*64]);
        }
    };

    stage(0, 0);

    f32x16 o0a, o1a, o0b, o1b, z;
    #pragma unroll
    for (int r = 0; r < 16; r++){ o0a[r]=0.f; o1a[r]=0.f; o0b[r]=0.f; o1b[r]=0.f; z[r]=0.f; }
    float lsA = 0.f, lsB = 0.f;

    const char* KbA = (const char*)&Kl[0][0] + (w*32 + ln)*128;
    const char* VbA = (const char*)&Vl[0][0] + ln*128;
    int swzr = (ln & 7) << 4;

    for (int kt = 0; kt < 64; kt++){
        asm volatile("s_waitcnt vmcnt(0)" ::: "memory");
        __builtin_amdgcn_s_barrier();
        __builtin_amdgcn_sched_barrier(0);
        if (kt < 63) stage((kt + 1) & 1, kt + 1);
        __builtin_amdgcn_sched_barrier(0);

        int boff = (kt & 1) * (64*64*2);

        f32x16 sA, sB;
        {
            int cb = (hi*16) ^ swzr;
            bf16x8 ak = *(const bf16x8*)(KbA + boff + cb);
            sA = MFMA32(ak, bqa[0], z);
            sB = MFMA32(ak, bqb[0], z);
        }
        __builtin_amdgcn_s_setprio(1);
        #pragma unroll
        for (int dsub = 1; dsub < 4; dsub++){
            int cb = (dsub*32 + hi*16) ^ swzr;
            bf16x8 ak = *(const bf16x8*)(KbA + boff + cb);
            sA = MFMA32(ak, bqa[dsub], sA);
            sB = MFMA32(ak, bqb[dsub], sB);
        }
        __builtin_amdgcn_s_setprio(0);

        #pragma unroll
        for (int r = 0; r < 16; r++){ sA[r] = __builtin_amdgcn_exp2f(sA[r]); lsA += sA[r]; }
        #pragma unroll
        for (int r = 0; r < 16; r++){ sB[r] = __builtin_amdgcn_exp2f(sB[r]); lsB += sB[r]; }

        __builtin_amdgcn_s_setprio(1);
        #pragma unroll
        for (int hsel = 0; hsel < 2; hsel++){
            int obp = hsel * 8;
            int a0 = cvtpk(sA[obp+0], sA[obp+1]);
            int a1 = cvtpk(sA[obp+2], sA[obp+3]);
            int c0 = cvtpk(sA[obp+4], sA[obp+5]);
            int c1 = cvtpk(sA[obp+6], sA[obp+7]);
            plswap(a0, c0);
            plswap(a1, c1);
            union { int i[4]; bf16x8 v; } fuA;
            fuA.i[0] = a0; fuA.i[1] = a1; fuA.i[2] = c0; fuA.i[3] = c1;

            int d0 = cvtpk(sB[obp+0], sB[obp+1]);
            int d1 = cvtpk(sB[obp+2], sB[obp+3]);
            int e0 = cvtpk(sB[obp+4], sB[obp+5]);
            int e1 = cvtpk(sB[obp+6], sB[obp+7]);
            plswap(d0, e0);
            plswap(d1, e1);
            union { int i[4]; bf16x8 v; } fuB;
            fuB.i[0] = d0; fuB.i[1] = d1; fuB.i[2] = e0; fuB.i[3] = e1;

            int cb = ((w*4 + hsel*2 + hi) << 4) ^ swzr;
            bf16x8 av0 = *(const bf16x8*)(VbA + boff + cb);
            bf16x8 av1 = *(const bf16x8*)(VbA + boff + 32*128 + cb);
            o0a = MFMA32(av0, fuA.v, o0a);
            o1a = MFMA32(av1, fuA.v, o1a);
            o0b = MFMA32(av0, fuB.v, o0b);
            o1b = MFMA32(av1, fuB.v, o1b);
        }
        __builtin_amdgcn_s_setprio(0);
    }

    lsA += __shfl_xor(lsA, 32);
    lsB += __shfl_xor(lsB, 32);
    __syncthreads();
    float* m1 = (float*)&Kl[0][0];
    float* m2 = (float*)&Vl[0][0];
    if (w == 1){
        #pragma unroll
        for (int r = 0; r < 16; r++){
            m1[r*64 + lane]        = o0a[r];
            m1[1024 + r*64 + lane] = o1a[r];
            m2[r*64 + lane]        = o0b[r];
            m2[1024 + r*64 + lane] = o1b[r];
        }
        if (hi == 0){ m2[2048 + ln] = lsA; m2[2048 + 32 + ln] = lsB; }
    }
    __syncthreads();
    if (w == 0){
        #pragma unroll
        for (int r = 0; r < 16; r++){
            o0a[r] += m1[r*64 + lane];
            o1a[r] += m1[1024 + r*64 + lane];
            o0b[r] += m2[r*64 + lane];
            o1b[r] += m2[1024 + r*64 + lane];
        }
        float rA = 1.0f / (lsA + m2[2048 + ln]);
        float rB = 1.0f / (lsB + m2[2048 + 32 + ln]);
        int b = bh >> 3, h = bh & 7;
        unsigned short* dstA = O + (size_t)(b*4096 + q0 + ln)*512      + h*64;
        unsigned short* dstB = O + (size_t)(b*4096 + q0 + 32 + ln)*512 + h*64;
        #pragma unroll
        for (int m = 0; m < 2; m++){
            const f32x16& ovA = m ? o1a : o0a;
            const f32x16& ovB = m ? o1b : o0b;
            #pragma unroll
            for (int g = 0; g < 4; g++){
                int d = m*32 + g*8 + hi*4;
                ushort4v pkA, pkB;
                #pragma unroll
                for (int j = 0; j < 4; j++){
                    pkA[j] = f2bf(ovA[g*4 + j] * rA);
                    pkB[j] = f2bf(ovB[g*4 + j] * rB);
                }
                *(ushort4v*)(dstA + d) = pkA;
                *(ushort4v*)(dstB + d) = pkB;
            }
        }
    }
}

// ---------------------------------------------------------------- launch
extern "C" void kernel_launch(void* const* d_in, const int* in_sizes, int n_in,
                              void* d_out, int out_size, void* d_ws, size_t ws_size,
                              hipStream_t stream) {
    const float* q    = (const float*)d_in[0];
    const float* gn_w = (const float*)d_in[1];
    const float* gn_b = (const float*)d_in[2];
    const float* wq   = (const float*)d_in[3];
    const float* bq   = (const float*)d_in[4];
    const float* wk   = (const float*)d_in[5];
    const float* bk   = (const float*)d_in[6];
    const float* wv   = (const float*)d_in[7];
    const float* bv   = (const float*)d_in[8];
    const float* wo   = (const float*)d_in[9];
    const float* bo   = (const float*)d_in[10];
    float* outp = (float*)d_out;

    char* ws = (char*)d_ws;
    float2v* parts = (float2v*)ws;                 // 512 x float2 = 4 KB
    unsigned short* xn  = (unsigned short*)(ws + 8192);
    const size_t TOK = (size_t)8192 * 512;
    unsigned short* wqkb = xn + TOK;               // 1024 x 512
    unsigned short* wvb  = wqkb + 1024*512;
    unsigned short* wob  = wvb + 512*512;
    unsigned short* Qb   = wob + 512*512;
    unsigned short* Kb   = Qb + TOK;
    unsigned short* Vt   = Kb + TOK;
    unsigned short* Ob   = Vt + TOK;

    gn_stats_wconv<<<1536, 256, 0, stream>>>(q, parts, wq, wk, wv, wo, wqkb, wvb, wob);
    gn_apply<<<dim3(64, 8, 2), 256, 0, stream>>>(q, parts, gn_w, gn_b, xn);
    gemm_qkv<<<1024, 256, 0, stream>>>(xn, wqkb, wvb, bq, bk, bv, Qb, Kb, Vt);
    attn5<<<1024, 128, 0, stream>>>(Qb, Kb, Vt, Ob);
    gemm_o2<<<dim3(64, 8), 256, 0, stream>>>(wob, Ob, bo, q, outp);
}

// Round 11
// 134.520 us; speedup vs baseline: 1.2681x; 1.0046x over previous
//
#include <hip/hip_runtime.h>
#include <hip/hip_bf16.h>
#include <cstdint>
#include <cstddef>

using bf16x8   = __attribute__((ext_vector_type(8))) short;
using f32x4    = __attribute__((ext_vector_type(4))) float;
using f32x16   = __attribute__((ext_vector_type(16))) float;
using ushort8  = __attribute__((ext_vector_type(8))) unsigned short;
using ushort4v = __attribute__((ext_vector_type(4))) unsigned short;
using float4v  = __attribute__((ext_vector_type(4))) float;
using float2v  = __attribute__((ext_vector_type(2))) float;

#define MFMA16(a,b,c) __builtin_amdgcn_mfma_f32_16x16x32_bf16((a),(b),(c),0,0,0)
#define MFMA32(a,b,c) __builtin_amdgcn_mfma_f32_32x32x16_bf16((a),(b),(c),0,0,0)

#define QSCALE 0.18033688011112042f   // log2(e)/8

__device__ __forceinline__ unsigned short f2bf(float f){
    union { float f; unsigned u; } v; v.f = f;
    unsigned r = v.u + 0x7FFFu + ((v.u >> 16) & 1u);
    return (unsigned short)(r >> 16);
}

__device__ __forceinline__ int cvtpk(float lo, float hi){
    int r;
    asm volatile("v_cvt_pk_bf16_f32 %0, %1, %2" : "=v"(r) : "v"(lo), "v"(hi));
    return r;
}

#if __has_builtin(__builtin_amdgcn_permlane32_swap)
__device__ __forceinline__ void plswap(int &a, int &b){
    auto r = __builtin_amdgcn_permlane32_swap(a, b, false, false);
    a = r[0]; b = r[1];
}
#else
__device__ __forceinline__ void plswap(int &a, int &b){
    int ta = __shfl_xor(a, 32), tb = __shfl_xor(b, 32);
    bool hi = ((threadIdx.x & 63) >= 32);
    int na = hi ? tb : a;
    int nb = hi ? b  : ta;
    a = na; b = nb;
}
#endif

__device__ __forceinline__ void gload16(const unsigned short* g, unsigned short* l){
    __builtin_amdgcn_global_load_lds(
        (const __attribute__((address_space(1))) void*)g,
        (__attribute__((address_space(3))) void*)l,
        16, 0, 0);
}

// ---------------------------------------------------------------- GN partial stats + wconv merged
__global__ __launch_bounds__(256) void gn_stats_wconv(const float* __restrict__ x,
                                                      float2v* __restrict__ parts,
                                                      const float* __restrict__ w0, const float* __restrict__ w1,
                                                      const float* __restrict__ w2, const float* __restrict__ w3,
                                                      unsigned short* wqk, unsigned short* wv, unsigned short* wo){
    int bid = blockIdx.x;
    if (bid < 512){
        const float4v* p4 = (const float4v*)(x + (size_t)bid * 8192);
        float s = 0.f, ss = 0.f;
        #pragma unroll
        for (int i = 0; i < 8; i++){
            float4v v = p4[i*256 + threadIdx.x];
            s  += v[0]+v[1]+v[2]+v[3];
            ss += v[0]*v[0]+v[1]*v[1]+v[2]*v[2]+v[3]*v[3];
        }
        __shared__ float ls[4], lss[4];
        int lane = threadIdx.x & 63, w = threadIdx.x >> 6;
        #pragma unroll
        for (int o = 32; o > 0; o >>= 1){ s += __shfl_down(s, o); ss += __shfl_down(ss, o); }
        if (lane == 0){ ls[w] = s; lss[w] = ss; }
        __syncthreads();
        if (threadIdx.x == 0){
            float2v p;
            p[0] = ls[0]+ls[1]+ls[2]+ls[3];
            p[1] = lss[0]+lss[1]+lss[2]+lss[3];
            parts[bid] = p;
        }
    } else {
        int i2 = bid - 512;
        int y = i2 >> 8, bx = i2 & 255;
        const float* src; unsigned short* dst; float sc = 1.0f;
        switch (y){
            case 0: src = w0; dst = wqk;          sc = QSCALE; break;
            case 1: src = w1; dst = wqk + 512*512; break;
            case 2: src = w2; dst = wv; break;
            default: src = w3; dst = wo; break;
        }
        int i = (bx*256 + threadIdx.x) * 4;
        float4v v = *(const float4v*)(src + i);
        ushort4v o;
        #pragma unroll
        for (int j = 0; j < 4; j++) o[j] = f2bf(v[j]*sc);
        *(ushort4v*)(dst + i) = o;
    }
}

// normalize + transpose; folds the 8 partials per group inline (deterministic).
__global__ __launch_bounds__(256) void gn_apply(const float* __restrict__ x,
                                                const float2v* __restrict__ parts,
                                                const float* __restrict__ gw,
                                                const float* __restrict__ gb,
                                                unsigned short* __restrict__ xn){
    int b = blockIdx.z, c0 = blockIdx.y * 64, n0 = blockIdx.x * 64;
    __shared__ unsigned short tile[64][68];
    __shared__ float gmean[4], grstd[4];
    if (threadIdx.x < 4){
        int g = b*32 + (c0 >> 4) + threadIdx.x;
        float s = 0.f, ss = 0.f;
        #pragma unroll
        for (int e = 0; e < 8; e++){
            float2v p = parts[g*8 + e];
            s += p[0]; ss += p[1];
        }
        float m = s * (1.f/65536.f);
        float var = ss * (1.f/65536.f) - m*m;
        gmean[threadIdx.x] = m;
        grstd[threadIdx.x] = rsqrtf(var + 1e-5f);
    }
    __syncthreads();
    for (int i = threadIdx.x; i < 64*16; i += 256){
        int row = i >> 4, f4 = i & 15;
        int c = c0 + row;
        int gl = row >> 4;
        float rs = grstd[gl];
        float wgt = gw[c] * rs;
        float bia = gb[c] - gmean[gl] * wgt;
        float4v v = *(const float4v*)(x + ((size_t)(b*512 + c))*4096 + n0 + f4*4);
        ushort4v o;
        #pragma unroll
        for (int j = 0; j < 4; j++) o[j] = f2bf(v[j]*wgt + bia);
        *(ushort4v*)&tile[row][f4*4] = o;
    }
    __syncthreads();
    for (int i = threadIdx.x; i < 64*8; i += 256){
        int nr = i >> 3, c8 = i & 7;
        ushort8 o;
        #pragma unroll
        for (int j = 0; j < 8; j++) o[j] = tile[c8*8 + j][nr];
        *(ushort8*)(xn + ((size_t)(b*4096 + n0 + nr))*512 + c0 + c8*8) = o;
    }
}

// ---------------------------------------------------------------- fused QKV projections
__global__ __launch_bounds__(256) void gemm_qkv(const unsigned short* __restrict__ xn,
                                                const unsigned short* __restrict__ wqk,
                                                const unsigned short* __restrict__ Wv,
                                                const float* __restrict__ bq,
                                                const float* __restrict__ bk,
                                                const float* __restrict__ bv,
                                                unsigned short* __restrict__ Q,
                                                unsigned short* __restrict__ K,
                                                unsigned short* __restrict__ Vt){
    __shared__ unsigned short Al[128*32];
    __shared__ unsigned short Bl[128*32];
    int bid = blockIdx.x;
    int t = threadIdx.x, lane = t & 63, w = t >> 6;
    int wr = w >> 1, wc = w & 1;
    int lr = lane >> 2, lc = lane & 3;

    if (bid < 512){
        int m0 = (bid & 63) * 128, n0 = (bid >> 6) * 128;
        f32x4 acc[4][4] = {};
        const unsigned short* Asrc = xn  + (size_t)(m0 + w*32 + lr)*512 + lc*8;
        const unsigned short* Bsrc = wqk + (size_t)(n0 + w*32 + lr)*512 + lc*8;
        unsigned short* Adst = &Al[(w*32)*32];
        unsigned short* Bdst = &Bl[(w*32)*32];

        for (int ks = 0; ks < 16; ks++){
            gload16(Asrc + ks*32,          Adst);
            gload16(Asrc + ks*32 + 16*512, Adst + 16*32);
            gload16(Bsrc + ks*32,          Bdst);
            gload16(Bsrc + ks*32 + 16*512, Bdst + 16*32);
            asm volatile("s_waitcnt vmcnt(0)" ::: "memory");
            __syncthreads();
            bf16x8 a[4], b[4];
            #pragma unroll
            for (int mi = 0; mi < 4; mi++) a[mi] = *(bf16x8*)&Al[(wr*64 + mi*16 + (lane&15))*32 + (lane>>4)*8];
            #pragma unroll
            for (int ni = 0; ni < 4; ni++) b[ni] = *(bf16x8*)&Bl[(wc*64 + ni*16 + (lane&15))*32 + (lane>>4)*8];
            #pragma unroll
            for (int mi = 0; mi < 4; mi++)
                #pragma unroll
                for (int ni = 0; ni < 4; ni++)
                    acc[mi][ni] = MFMA16(a[mi], b[ni], acc[mi][ni]);
            __syncthreads();
        }

        int cK = n0 >> 9;
        const float* bias = cK ? bk : bq;
        unsigned short* dst0 = cK ? K : Q;
        float bsc = cK ? 1.0f : QSCALE;
        #pragma unroll
        for (int mi = 0; mi < 4; mi++)
            #pragma unroll
            for (int ni = 0; ni < 4; ni++)
                #pragma unroll
                for (int r = 0; r < 4; r++){
                    int mrow = m0 + wr*64 + mi*16 + (lane>>4)*4 + r;
                    int col  = (n0 & 511) + wc*64 + ni*16 + (lane&15);
                    int b_ = mrow >> 12, n = mrow & 4095;
                    int h = col >> 6, d = col & 63;
                    float v = acc[mi][ni][r] + bias[col]*bsc;
                    dst0[(size_t)((b_*8+h)*4096 + n)*64 + d] = f2bf(v);
                }
    } else {
        int i2 = bid - 512;
        int m0 = (i2 >> 6) * 64, n0 = (i2 & 63) * 128;
        f32x4 acc[2][4] = {};
        const unsigned short* Asrc = Wv + (size_t)(m0 + w*16 + lr)*512 + lc*8;
        const unsigned short* Bsrc = xn + (size_t)(n0 + w*32 + lr)*512 + lc*8;
        unsigned short* Adst = &Al[(w*16)*32];
        unsigned short* Bdst = &Bl[(w*32)*32];

        for (int ks = 0; ks < 16; ks++){
            gload16(Asrc + ks*32,          Adst);
            gload16(Bsrc + ks*32,          Bdst);
            gload16(Bsrc + ks*32 + 16*512, Bdst + 16*32);
            asm volatile("s_waitcnt vmcnt(0)" ::: "memory");
            __syncthreads();
            bf16x8 a[2], b[4];
            #pragma unroll
            for (int mi = 0; mi < 2; mi++) a[mi] = *(bf16x8*)&Al[(wr*32 + mi*16 + (lane&15))*32 + (lane>>4)*8];
            #pragma unroll
            for (int ni = 0; ni < 4; ni++) b[ni] = *(bf16x8*)&Bl[(wc*64 + ni*16 + (lane&15))*32 + (lane>>4)*8];
            #pragma unroll
            for (int mi = 0; mi < 2; mi++)
                #pragma unroll
                for (int ni = 0; ni < 4; ni++)
                    acc[mi][ni] = MFMA16(a[mi], b[ni], acc[mi][ni]);
            __syncthreads();
        }
        #pragma unroll
        for (int mi = 0; mi < 2; mi++)
            #pragma unroll
            for (int ni = 0; ni < 4; ni++)
                #pragma unroll
                for (int r = 0; r < 4; r++){
                    int row  = m0 + wr*32 + mi*16 + (lane>>4)*4 + r;
                    int colm = n0 + wc*64 + ni*16 + (lane&15);
                    int b_ = colm >> 12, n = colm & 4095;
                    int h = row >> 6, d = row & 63;
                    float v = acc[mi][ni][r] + bv[row];
                    Vt[(size_t)((b_*8+h)*64 + d)*4096 + n] = f2bf(v);
                }
    }
}

// ---------------------------------------------------------------- output projection + residual
__global__ __launch_bounds__(256) void gemm_o2(const unsigned short* __restrict__ Wo,
                                               const unsigned short* __restrict__ Om,
                                               const float* __restrict__ bo,
                                               const float* __restrict__ resid,
                                               float* __restrict__ outp){
    __shared__ unsigned short Al[64*32];
    __shared__ unsigned short Bl[128*32];
    int t = threadIdx.x, lane = t & 63, w = t >> 6;
    int wr = w >> 1, wc = w & 1;
    int m0 = blockIdx.y * 64, n0 = blockIdx.x * 128;
    int lr = lane >> 2, lc = lane & 3;
    f32x4 acc[2][4] = {};

    const unsigned short* Asrc = Wo + (size_t)(m0 + w*16 + lr)*512 + lc*8;
    const unsigned short* Bsrc = Om + (size_t)(n0 + w*32 + lr)*512 + lc*8;
    unsigned short* Adst = &Al[(w*16)*32];
    unsigned short* Bdst = &Bl[(w*32)*32];

    for (int ks = 0; ks < 16; ks++){
        gload16(Asrc + ks*32,          Adst);
        gload16(Bsrc + ks*32,          Bdst);
        gload16(Bsrc + ks*32 + 16*512, Bdst + 16*32);
        asm volatile("s_waitcnt vmcnt(0)" ::: "memory");
        __syncthreads();
        bf16x8 a[2], b[4];
        #pragma unroll
        for (int mi = 0; mi < 2; mi++) a[mi] = *(bf16x8*)&Al[(wr*32 + mi*16 + (lane&15))*32 + (lane>>4)*8];
        #pragma unroll
        for (int ni = 0; ni < 4; ni++) b[ni] = *(bf16x8*)&Bl[(wc*64 + ni*16 + (lane&15))*32 + (lane>>4)*8];
        #pragma unroll
        for (int mi = 0; mi < 2; mi++)
            #pragma unroll
            for (int ni = 0; ni < 4; ni++)
                acc[mi][ni] = MFMA16(a[mi], b[ni], acc[mi][ni]);
        __syncthreads();
    }
    #pragma unroll
    for (int mi = 0; mi < 2; mi++)
        #pragma unroll
        for (int ni = 0; ni < 4; ni++)
            #pragma unroll
            for (int r = 0; r < 4; r++){
                int row  = m0 + wr*32 + mi*16 + (lane>>4)*4 + r;
                int colm = n0 + wc*64 + ni*16 + (lane&15);
                int b_ = colm >> 12, n = colm & 4095;
                size_t oi = ((size_t)(b_*512 + row))*4096 + n;
                outp[oi] = acc[mi][ni][r] + bo[row] + resid[oi];
            }
}

// ---------------------------------------------------------------- flash attention v9: barrier-free attn5
// 2 waves kv-split, but V staged into PER-WAVE kv-banks so all K/V LDS traffic is
// wave-local -> the 64 per-tile barriers are deleted; sync is per-wave counted
// vmcnt(8) with 2-tile-deep prefetch. Waves free-run and de-phase (pipe overlap).
__global__ __launch_bounds__(128, 2) void attn9(const unsigned short* __restrict__ Q,
                                                const unsigned short* __restrict__ K,
                                                const unsigned short* __restrict__ Vt,
                                                unsigned short* __restrict__ O){
    int bid = blockIdx.x;
    int idx = bid >> 3;
    int bh = ((bid & 7) << 1) | (idx >> 6);
    int qt = idx & 63;
    int t = threadIdx.x, lane = t & 63, w = t >> 6;   // w = kv-half
    int ln = lane & 31, hi = lane >> 5;
    int q0 = qt * 64;

    __shared__ unsigned short Kl[2][64*64];        // [buf][kv 64][d 64]  (wave w owns rows w*32..)
    __shared__ unsigned short Vl[2][2][64*32];     // [buf][wave][d 64][kv 32]  (64B rows)

    const unsigned short* Qb = Q  + (size_t)bh * 4096 * 64;
    const unsigned short* Kb = K  + (size_t)bh * 4096 * 64;
    const unsigned short* Vb = Vt + (size_t)bh * 64 * 4096;

    bf16x8 bqa[4], bqb[4];
    #pragma unroll
    for (int dsub = 0; dsub < 4; dsub++){
        bqa[dsub] = *(const bf16x8*)(Qb + (size_t)(q0 + ln)*64      + dsub*16 + hi*8);
        bqb[dsub] = *(const bf16x8*)(Qb + (size_t)(q0 + 32 + ln)*64 + dsub*16 + hi*8);
    }

    // K staging map (8 rows x 128B per gload16, slot XOR row)
    int srow = lane >> 3;
    int sswz = (lane & 7) ^ srow;
    // V staging map (16 rows x 64B per gload16): d = i*16 + (lane>>2), phys slot = lane&3,
    // logical kv-slot s = p ^ ((d>>1)&3); i*16 doesn't affect (d>>1)&3.
    int vdl = lane >> 2;
    int vsl = (lane & 3) ^ ((vdl >> 1) & 3);

    auto stage = [&](int kt){
        int kv0 = kt * 64;
        unsigned short* kdst = &Kl[kt & 1][0];
        #pragma unroll
        for (int i = 0; i < 4; i++){
            int r0 = w*32 + i*8;
            gload16(Kb + (size_t)(kv0 + r0 + srow)*64 + sswz*8, kdst + r0*64);
        }
        unsigned short* vdst = &Vl[kt & 1][w][0];
        #pragma unroll
        for (int i = 0; i < 4; i++)
            gload16(Vb + (size_t)(i*16 + vdl)*4096 + kv0 + w*32 + vsl*8, vdst + i*512);
    };

    stage(0);
    stage(1);

    f32x16 o0a, o1a, o0b, o1b, z;
    #pragma unroll
    for (int r = 0; r < 16; r++){ o0a[r]=0.f; o1a[r]=0.f; o0b[r]=0.f; o1b[r]=0.f; z[r]=0.f; }
    float lsA = 0.f, lsB = 0.f;

    const char* KbA = (const char*)&Kl[0][0] + (w*32 + ln)*128;
    int swzr = (ln & 7) << 4;
    const char* VbW = (const char*)&Vl[0][w][0];
    int vrswz = (ln >> 1) & 3;   // same for d=ln and d=32+ln

    for (int kt = 0; kt < 64; kt++){
        if (kt < 63) asm volatile("s_waitcnt vmcnt(8)" ::: "memory");
        else         asm volatile("s_waitcnt vmcnt(0)" ::: "memory");
        __builtin_amdgcn_sched_barrier(0);

        int kboff = (kt & 1) * (64*64*2);
        int vboff = (kt & 1) * (2*64*32*2);

        // ---- QK^T (swapped), wave-local K rows
        f32x16 sA, sB;
        {
            int cb = (hi*16) ^ swzr;
            bf16x8 ak = *(const bf16x8*)(KbA + kboff + cb);
            sA = MFMA32(ak, bqa[0], z);
            sB = MFMA32(ak, bqb[0], z);
        }
        __builtin_amdgcn_s_setprio(1);
        #pragma unroll
        for (int dsub = 1; dsub < 4; dsub++){
            int cb = (dsub*32 + hi*16) ^ swzr;
            bf16x8 ak = *(const bf16x8*)(KbA + kboff + cb);
            sA = MFMA32(ak, bqa[dsub], sA);
            sB = MFMA32(ak, bqb[dsub], sB);
        }
        __builtin_amdgcn_s_setprio(0);

        // ---- p = exp2(s); row-sums
        #pragma unroll
        for (int r = 0; r < 16; r++){ sA[r] = __builtin_amdgcn_exp2f(sA[r]); lsA += sA[r]; }
        #pragma unroll
        for (int r = 0; r < 16; r++){ sB[r] = __builtin_amdgcn_exp2f(sB[r]); lsB += sB[r]; }

        // ---- PV (swapped), wave-local V bank
        __builtin_amdgcn_s_setprio(1);
        #pragma unroll
        for (int hsel = 0; hsel < 2; hsel++){
            int obp = hsel * 8;
            int a0 = cvtpk(sA[obp+0], sA[obp+1]);
            int a1 = cvtpk(sA[obp+2], sA[obp+3]);
            int c0 = cvtpk(sA[obp+4], sA[obp+5]);
            int c1 = cvtpk(sA[obp+6], sA[obp+7]);
            plswap(a0, c0);
            plswap(a1, c1);
            union { int i[4]; bf16x8 v; } fuA;
            fuA.i[0] = a0; fuA.i[1] = a1; fuA.i[2] = c0; fuA.i[3] = c1;

            int d0 = cvtpk(sB[obp+0], sB[obp+1]);
            int d1 = cvtpk(sB[obp+2], sB[obp+3]);
            int e0 = cvtpk(sB[obp+4], sB[obp+5]);
            int e1 = cvtpk(sB[obp+6], sB[obp+7]);
            plswap(d0, e0);
            plswap(d1, e1);
            union { int i[4]; bf16x8 v; } fuB;
            fuB.i[0] = d0; fuB.i[1] = d1; fuB.i[2] = e0; fuB.i[3] = e1;

            int p0 = (((hsel*2 + hi) ^ vrswz) << 4);
            bf16x8 av0 = *(const bf16x8*)(VbW + vboff + ln*64 + p0);
            bf16x8 av1 = *(const bf16x8*)(VbW + vboff + (32 + ln)*64 + p0);
            o0a = MFMA32(av0, fuA.v, o0a);
            o1a = MFMA32(av1, fuA.v, o1a);
            o0b = MFMA32(av0, fuB.v, o0b);
            o1b = MFMA32(av1, fuB.v, o1b);
        }
        __builtin_amdgcn_s_setprio(0);

        __builtin_amdgcn_sched_barrier(0);
        if (kt < 62) stage(kt + 2);
        __builtin_amdgcn_sched_barrier(0);
    }

    // ---- merge kv-halves via LDS, normalize, store
    lsA += __shfl_xor(lsA, 32);
    lsB += __shfl_xor(lsB, 32);
    __syncthreads();
    float* m1 = (float*)&Kl[0][0];
    float* m2 = (float*)&Vl[0][0][0];
    if (w == 1){
        #pragma unroll
        for (int r = 0; r < 16; r++){
            m1[r*64 + lane]        = o0a[r];
            m1[1024 + r*64 + lane] = o1a[r];
            m2[r*64 + lane]        = o0b[r];
            m2[1024 + r*64 + lane] = o1b[r];
        }
        if (hi == 0){ m2[2048 + ln] = lsA; m2[2048 + 32 + ln] = lsB; }
    }
    __syncthreads();
    if (w == 0){
        #pragma unroll
        for (int r = 0; r < 16; r++){
            o0a[r] += m1[r*64 + lane];
            o1a[r] += m1[1024 + r*64 + lane];
            o0b[r] += m2[r*64 + lane];
            o1b[r] += m2[1024 + r*64 + lane];
        }
        float rA = 1.0f / (lsA + m2[2048 + ln]);
        float rB = 1.0f / (lsB + m2[2048 + 32 + ln]);
        int b = bh >> 3, h = bh & 7;
        unsigned short* dstA = O + (size_t)(b*4096 + q0 + ln)*512      + h*64;
        unsigned short* dstB = O + (size_t)(b*4096 + q0 + 32 + ln)*512 + h*64;
        #pragma unroll
        for (int m = 0; m < 2; m++){
            const f32x16& ovA = m ? o1a : o0a;
            const f32x16& ovB = m ? o1b : o0b;
            #pragma unroll
            for (int g = 0; g < 4; g++){
                int d = m*32 + g*8 + hi*4;
                ushort4v pkA, pkB;
                #pragma unroll
                for (int j = 0; j < 4; j++){
                    pkA[j] = f2bf(ovA[g*4 + j] * rA);
                    pkB[j] = f2bf(ovB[g*4 + j] * rB);
                }
                *(ushort4v*)(dstA + d) = pkA;
                *(ushort4v*)(dstB + d) = pkB;
            }
        }
    }
}

// ---------------------------------------------------------------- launch
extern "C" void kernel_launch(void* const* d_in, const int* in_sizes, int n_in,
                              void* d_out, int out_size, void* d_ws, size_t ws_size,
                              hipStream_t stream) {
    const float* q    = (const float*)d_in[0];
    const float* gn_w = (const float*)d_in[1];
    const float* gn_b = (const float*)d_in[2];
    const float* wq   = (const float*)d_in[3];
    const float* bq   = (const float*)d_in[4];
    const float* wk   = (const float*)d_in[5];
    const float* bk   = (const float*)d_in[6];
    const float* wv   = (const float*)d_in[7];
    const float* bv   = (const float*)d_in[8];
    const float* wo   = (const float*)d_in[9];
    const float* bo   = (const float*)d_in[10];
    float* outp = (float*)d_out;

    char* ws = (char*)d_ws;
    float2v* parts = (float2v*)ws;                 // 512 x float2 = 4 KB
    unsigned short* xn  = (unsigned short*)(ws + 8192);
    const size_t TOK = (size_t)8192 * 512;
    unsigned short* wqkb = xn + TOK;               // 1024 x 512
    unsigned short* wvb  = wqkb + 1024*512;
    unsigned short* wob  = wvb + 512*512;
    unsigned short* Qb   = wob + 512*512;
    unsigned short* Kb   = Qb + TOK;
    unsigned short* Vt   = Kb + TOK;
    unsigned short* Ob   = Vt + TOK;

    gn_stats_wconv<<<1536, 256, 0, stream>>>(q, parts, wq, wk, wv, wo, wqkb, wvb, wob);
    gn_apply<<<dim3(64, 8, 2), 256, 0, stream>>>(q, parts, gn_w, gn_b, xn);
    gemm_qkv<<<1024, 256, 0, stream>>>(xn, wqkb, wvb, bq, bk, bv, Qb, Kb, Vt);
    attn9<<<1024, 128, 0, stream>>>(Qb, Kb, Vt, Ob);
    gemm_o2<<<dim3(64, 8), 256, 0, stream>>>(wob, Ob, bo, q, outp);
}